// Round 8
// baseline (6168.193 us; speedup 1.0000x reference)
//
#include <hip/hip_runtime.h>
#include <hip/hip_fp16.h>

typedef _Float16 half8 __attribute__((ext_vector_type(8)));
typedef float f32x4 __attribute__((ext_vector_type(4)));
typedef unsigned long long u64;

#define B_ 256
#define SEQ_ 512
#define D_ 256
#define H_ 1024
#define C_ 10
#define S_ 511
#define KB_ 40      // K=1280 / 32
#define NPK_ 2048   // packed output cols per direction (g|i interleaved per 64)
#define NTF_ 128    // NPK/16 fine n-tiles
#define LP_ 84      // LDS row stride (floats): 86,016B total -> 1 block/CU (proven shape)

// ---- workspace byte offsets ----
#define WPK_HALVES (2*KB_*NTF_*512)                    // 5,242,880 halves
#define EMBH_OFF   (WPK_HALVES*2)                      // 10,485,760
#define EMBH_HALVES (SEQ_*D_)                          // 131,072
#define HPK_OFF    (EMBH_OFF + EMBH_HALVES*2)          // 10,747,904
#define HPK_PER_PAR (2*32*16*64*8)                     // 524,288 halves per parity (both dirs)
#define HFIN_OFF   (HPK_OFF + 2*HPK_PER_PAR*2)         // 12,845,056
#define HFIN_FLOATS (2*B_*H_)
#define BIAS_OFF   (HFIN_OFF + HFIN_FLOATS*4)
#define BAR_OFF    (BIAS_OFF + 2*NPK_*4)               // 8 groups x 32 flags x 16-word pad
#define BAR_WORDS  (8*32*16)
#define XT_OFF     (BAR_OFF + BAR_WORDS*4)             // transposed x: [SEQ][B] ints
#define XT_INTS    (SEQ_*B_)

__device__ __forceinline__ float fast_sigm(float x) {
    return __builtin_amdgcn_rcpf(1.f + __builtin_amdgcn_exp2f(-1.442695041f * x));
}
__device__ __forceinline__ float fast_tanh(float x) {
    return 1.f - 2.f * __builtin_amdgcn_rcpf(1.f + __builtin_amdgcn_exp2f(2.885390082f * x));
}
__device__ __forceinline__ half8 load_h_uc(const _Float16* p) {
    u64 two[2];
    two[0] = __hip_atomic_load((const u64*)p,     __ATOMIC_RELAXED, __HIP_MEMORY_SCOPE_SYSTEM);
    two[1] = __hip_atomic_load((const u64*)p + 1, __ATOMIC_RELAXED, __HIP_MEMORY_SCOPE_SYSTEM);
    half8 r; __builtin_memcpy(&r, two, 16); return r;
}

// h-part MFMA loop with explicit 1-deep load pipeline: iteration kk+1's UC loads
// are issued BEFORE iteration kk's MFMAs (2-slot rotating A-frag buffer; after
// full unroll the compiler emits partial vmcnt waits, keeping 8 loads in flight).
template<int FH>
__device__ __forceinline__ void h_part_pipe(
    const _Float16* __restrict__ hrd, const half8 (&wfr)[10][4],
    f32x4 (&acc)[4][4], int kb0, int mtblk, int lane)
{
    half8 abuf[2][4];
    #pragma unroll
    for (int mt = 0; mt < 4; ++mt)
        abuf[FH & 1][mt] = load_h_uc(hrd + (size_t)(((kb0 + FH - 8)*16 + (mtblk*4 + mt))*64 + lane)*8);
    #pragma unroll
    for (int kk = FH; kk < 10; ++kk) {
        if (kk + 1 < 10) {
            #pragma unroll
            for (int mt = 0; mt < 4; ++mt)
                abuf[(kk + 1) & 1][mt] = load_h_uc(hrd + (size_t)(((kb0 + kk + 1 - 8)*16 + (mtblk*4 + mt))*64 + lane)*8);
        }
        #pragma unroll
        for (int mt = 0; mt < 4; ++mt) {
            #pragma unroll
            for (int nt = 0; nt < 4; ++nt)
                acc[mt][nt] = __builtin_amdgcn_mfma_f32_16x16x32_f16(abuf[kk & 1][mt], wfr[kk][nt], acc[mt][nt], 0, 0, 0);
        }
    }
}

// Pack fp32 weights -> fp16 MFMA B-fragment-direct layout, emb -> fp16, biases packed,
// x -> transposed xT[t][m], zero barrier flags (ws is re-poisoned before every call).
__global__ void convert_kernel(
    const int* __restrict__ x, const float* __restrict__ emb,
    const float* __restrict__ Wgx_f, const float* __restrict__ Wgh_f, const float* __restrict__ bg_f,
    const float* __restrict__ Wix_f, const float* __restrict__ Wih_f, const float* __restrict__ bi_f,
    const float* __restrict__ Wgx_b, const float* __restrict__ Wgh_b, const float* __restrict__ bg_b,
    const float* __restrict__ Wix_b, const float* __restrict__ Wih_b, const float* __restrict__ bi_b,
    _Float16* __restrict__ Wpk, _Float16* __restrict__ embh, float* __restrict__ biaspk,
    unsigned* __restrict__ bar, int* __restrict__ xT)
{
    int idx = blockIdx.x * 256 + threadIdx.x;
    if (idx < WPK_HALVES) {
        int j = idx & 7;
        int L = (idx >> 3) & 63;
        int rest = idx >> 9;
        int ntf = rest & (NTF_ - 1);
        int rest2 = rest >> 7;
        int kb = rest2 % KB_;
        int d  = rest2 / KB_;
        int k = kb*32 + ((L >> 4) << 3) + j;
        int p = (ntf << 4) + (L & 15);
        int gate = (p >> 5) & 1;
        int u = ((p >> 6) << 5) + (p & 31);
        float v;
        if (k < D_) {
            const float* W = d ? (gate ? Wix_b : Wgx_b) : (gate ? Wix_f : Wgx_f);
            v = W[k*H_ + u];
        } else {
            const float* W = d ? (gate ? Wih_b : Wgh_b) : (gate ? Wih_f : Wgh_f);
            v = W[(k - D_)*H_ + u];
        }
        Wpk[idx] = (_Float16)v;
    } else if (idx < WPK_HALVES + EMBH_HALVES) {
        int i2 = idx - WPK_HALVES;
        embh[i2] = (_Float16)emb[i2];
    } else if (idx < WPK_HALVES + EMBH_HALVES + 2*NPK_) {
        int i3 = idx - (WPK_HALVES + EMBH_HALVES);
        int d = i3 >> 11;
        int p = i3 & (NPK_ - 1);
        int gate = (p >> 5) & 1;
        int u = ((p >> 6) << 5) + (p & 31);
        const float* bsrc = d ? (gate ? bi_b : bg_b) : (gate ? bi_f : bg_f);
        biaspk[i3] = bsrc[u];
    } else if (idx < WPK_HALVES + EMBH_HALVES + 2*NPK_ + BAR_WORDS) {
        bar[idx - (WPK_HALVES + EMBH_HALVES + 2*NPK_)] = 0u;
    } else if (idx < WPK_HALVES + EMBH_HALVES + 2*NPK_ + BAR_WORDS + XT_INTS) {
        int i5 = idx - (WPK_HALVES + EMBH_HALVES + 2*NPK_ + BAR_WORDS);
        int t = i5 >> 8;
        int m = i5 & (B_ - 1);
        xT[i5] = x[m*SEQ_ + t];
    }
}

// Persistent kernel (round-5 structure, proven 4.49ms): 256 blocks x 256 threads,
// 86KB LDS -> 1 block/CU. blockIdx = ntb*8 + group, group = dir*4 + mtblk.
// W + c-state in registers; h double-buffered, exchanged UC (system-scope);
// ONE consolidated all-32 flag wait per step (covers RAW+WAR); h-load loop is
// software-pipelined (the only change vs round 5).
__global__ __launch_bounds__(256, 1) void persistent_kernel(
    const int* __restrict__ xT, const _Float16* __restrict__ embh,
    const _Float16* __restrict__ Wpk, const float* __restrict__ biaspk,
    _Float16* __restrict__ hpk, float* __restrict__ hfinal,
    unsigned* __restrict__ bar)
{
    __shared__ float lds[4][64][LP_];

    int group = blockIdx.x & 7;
    int dir   = group >> 2;
    int mtblk = group & 3;
    int ntb   = blockIdx.x >> 3;
    int w    = threadIdx.x >> 6;
    int lane = threadIdx.x & 63;
    int q    = lane >> 4;
    int c16  = lane & 15;
    int u0   = q * 8;               // epilogue: 8 consecutive units per thread
    int kb0  = w * 10;              // wave w owns kbs [10w, 10w+10)

    unsigned* gflags = bar + group * (32*16);
    const _Float16* Wd = Wpk + (size_t)dir * (KB_*NTF_*512);

    // ---- preload W fragments into registers (160 VGPRs/lane) ----
    half8 wfr[10][4];
    #pragma unroll
    for (int kk = 0; kk < 10; ++kk) {
        #pragma unroll
        for (int nt = 0; nt < 4; ++nt)
            wfr[kk][nt] = *(const half8*)(Wd + (((size_t)(kb0 + kk)*NTF_ + (ntb*4 + nt))*64 + lane)*8);
    }

    // ---- preload epilogue biases ----
    float bgr[8], bir[8];
    #pragma unroll
    for (int j = 0; j < 8; ++j) {
        bgr[j] = biaspk[dir*NPK_ + ntb*64 + u0 + j];
        bir[j] = biaspk[dir*NPK_ + ntb*64 + 32 + u0 + j];
    }

    // ---- c-state in registers: thread owns (m = mtblk*64+w*16+c16, u = ntb*32+u0+j) ----
    float creg[8];
    #pragma unroll
    for (int j = 0; j < 8; ++j) creg[j] = 0.f;

    #pragma unroll 1
    for (int t = 0; t < S_; ++t) {
        const _Float16* hrd = hpk + (size_t)(t & 1) * HPK_PER_PAR + dir*(32*16*64*8);
        _Float16*       hwr = hpk + (size_t)((t & 1) ^ 1) * HPK_PER_PAR + dir*(32*16*64*8);
        int t_eff = dir ? (S_ - 1 - t) : t;

        int xr[4] = {0, 0, 0, 0};
        if (w == 0) {                         // only wave 0 handles the x-part kbs
            #pragma unroll
            for (int mt = 0; mt < 4; ++mt)
                xr[mt] = xT[t_eff*B_ + mtblk*64 + mt*16 + c16];
        }

        f32x4 acc[4][4];
        #pragma unroll
        for (int a = 0; a < 4; ++a)
            #pragma unroll
            for (int b = 0; b < 4; ++b) {
                acc[a][b][0] = 0.f; acc[a][b][1] = 0.f; acc[a][b][2] = 0.f; acc[a][b][3] = 0.f;
            }

        // ---- x-part (wave 0 only; independent of h, overlaps producer wait) ----
        #pragma unroll
        for (int kk = 0; kk < 10; ++kk) {
            int kb = kb0 + kk;
            if (kb < 8) {
                half8 a[4];
                #pragma unroll
                for (int mt = 0; mt < 4; ++mt)
                    a[mt] = *(const half8*)(embh + xr[mt]*D_ + kb*32 + q*8);
                #pragma unroll
                for (int mt = 0; mt < 4; ++mt) {
                    #pragma unroll
                    for (int nt = 0; nt < 4; ++nt)
                        acc[mt][nt] = __builtin_amdgcn_mfma_f32_16x16x32_f16(a[mt], wfr[kk][nt], acc[mt][nt], 0, 0, 0);
                }
            }
        }

        if (t > 0) {
            // ---- single consolidated wait: all 32 group flags >= t (RAW + WAR) ----
            {
                unsigned v = (unsigned)t;
                for (;;) {
                    if (lane < 32)
                        v = __hip_atomic_load(&gflags[lane*16], __ATOMIC_RELAXED, __HIP_MEMORY_SCOPE_SYSTEM);
                    if (__all(v >= (unsigned)t)) break;
                    __builtin_amdgcn_s_sleep(1);
                }
            }
            // ---- h-part: UC loads, software-pipelined 1 iteration ahead ----
            if (w == 0) h_part_pipe<8>(hrd, wfr, acc, kb0, mtblk, lane);
            else        h_part_pipe<0>(hrd, wfr, acc, kb0, mtblk, lane);
        }

        // K-split partials -> LDS
        #pragma unroll
        for (int mt = 0; mt < 4; ++mt) {
            #pragma unroll
            for (int nt = 0; nt < 4; ++nt) {
                #pragma unroll
                for (int r = 0; r < 4; ++r)
                    lds[w][mt*16 + q*4 + r][nt*16 + c16] = acc[mt][nt][r];
            }
        }
        __syncthreads();

        // Epilogue: thread -> (m_loc = w*16 + c16, units u0..u0+7). Cols: g = u_loc, i = 32+u_loc.
        {
            int mloc = w*16 + c16;
            int mg   = mtblk*64 + mloc;
            half8 hv;
            float hf[8];
            #pragma unroll
            for (int j = 0; j < 8; ++j) {
                float zg = lds[0][mloc][u0 + j] + lds[1][mloc][u0 + j]
                         + lds[2][mloc][u0 + j] + lds[3][mloc][u0 + j] + bgr[j];
                float zi = lds[0][mloc][32 + u0 + j] + lds[1][mloc][32 + u0 + j]
                         + lds[2][mloc][32 + u0 + j] + lds[3][mloc][32 + u0 + j] + bir[j];
                float g  = fast_tanh(zg);
                float ii = fast_sigm(zi);
                float cn = ii * (g + creg[j]);
                creg[j] = cn;
                float h = fast_tanh(cn) * ii;
                hv[j] = (_Float16)h;
                hf[j] = h;
            }
            // publish h: write-through (system-scope) stores into A-fragment layout.
            u64 two[2];
            __builtin_memcpy(two, &hv, 16);
            u64* base = (u64*)(hwr + ((size_t)((ntb*16 + mtblk*4 + w)*64 + lane) * 8));
            __hip_atomic_store(base,     two[0], __ATOMIC_RELAXED, __HIP_MEMORY_SCOPE_SYSTEM);
            __hip_atomic_store(base + 1, two[1], __ATOMIC_RELAXED, __HIP_MEMORY_SCOPE_SYSTEM);
            if (t == S_ - 1) {
                #pragma unroll
                for (int j = 0; j < 8; ++j)
                    hfinal[dir*(B_*H_) + mg*H_ + ntb*32 + u0 + j] = hf[j];
            }
        }

        // ---- publish completion flag (no cache maintenance) ----
        if (t != S_ - 1) {
            __builtin_amdgcn_s_waitcnt(0x0F70);   // vmcnt(0): this wave's UC h-stores acked at coherence point
            __syncthreads();                      // all 4 waves drained; also protects LDS reuse
            if (threadIdx.x == 0)
                __hip_atomic_store(&gflags[ntb*16], (unsigned)(t + 1), __ATOMIC_RELAXED, __HIP_MEMORY_SCOPE_SYSTEM);
        }
    }
}

// out[b][c] = [hf|hb] @ Wp + bp
__global__ void proj_kernel(const float* __restrict__ hfinal,
                            const float* __restrict__ Wp, const float* __restrict__ bp,
                            float* __restrict__ out)
{
    int b = blockIdx.x;
    int lane = threadIdx.x;
    float s[C_];
    #pragma unroll
    for (int c = 0; c < C_; ++c) s[c] = 0.f;
    for (int j = lane; j < 2*H_; j += 64) {
        float hv = (j < H_) ? hfinal[b*H_ + j] : hfinal[B_*H_ + b*H_ + (j - H_)];
        const float* wr = Wp + j*C_;
        #pragma unroll
        for (int c = 0; c < C_; ++c) s[c] += hv * wr[c];
    }
    #pragma unroll
    for (int off = 32; off > 0; off >>= 1) {
        #pragma unroll
        for (int c = 0; c < C_; ++c) s[c] += __shfl_down(s[c], off);
    }
    if (lane == 0) {
        #pragma unroll
        for (int c = 0; c < C_; ++c) out[b*C_ + c] = s[c] + bp[c];
    }
}

extern "C" void kernel_launch(void* const* d_in, const int* in_sizes, int n_in,
                              void* d_out, int out_size, void* d_ws, size_t ws_size,
                              hipStream_t stream)
{
    const int*   x     = (const int*)d_in[0];
    const float* emb   = (const float*)d_in[1];
    const float* Wgx_f = (const float*)d_in[2];
    const float* Wgh_f = (const float*)d_in[3];
    const float* bg_f  = (const float*)d_in[4];
    const float* Wix_f = (const float*)d_in[5];
    const float* Wih_f = (const float*)d_in[6];
    const float* bi_f  = (const float*)d_in[7];
    const float* Wgx_b = (const float*)d_in[8];
    const float* Wgh_b = (const float*)d_in[9];
    const float* bg_b  = (const float*)d_in[10];
    const float* Wix_b = (const float*)d_in[11];
    const float* Wih_b = (const float*)d_in[12];
    const float* bi_b  = (const float*)d_in[13];
    const float* Wp    = (const float*)d_in[14];
    const float* bp    = (const float*)d_in[15];
    float* out = (float*)d_out;

    char* ws = (char*)d_ws;
    _Float16* Wpk    = (_Float16*)(ws + 0);
    _Float16* embh   = (_Float16*)(ws + EMBH_OFF);
    _Float16* hpk    = (_Float16*)(ws + HPK_OFF);
    float*    hfinal = (float*)(ws + HFIN_OFF);
    float*    biaspk = (float*)(ws + BIAS_OFF);
    unsigned* bar    = (unsigned*)(ws + BAR_OFF);
    int*      xT     = (int*)(ws + XT_OFF);

    int total = WPK_HALVES + EMBH_HALVES + 2*NPK_ + BAR_WORDS + XT_INTS;
    convert_kernel<<<(total + 255)/256, 256, 0, stream>>>(
        x, emb, Wgx_f, Wgh_f, bg_f, Wix_f, Wih_f, bi_f,
        Wgx_b, Wgh_b, bg_b, Wix_b, Wih_b, bi_b, Wpk, embh, biaspk, bar, xT);

    persistent_kernel<<<256, 256, 0, stream>>>(xT, embh, Wpk, biaspk, hpk, hfinal, bar);

    proj_kernel<<<B_, 64, 0, stream>>>(hfinal, Wp, bp, out);
}

// Round 9
// 4544.009 us; speedup vs baseline: 1.3574x; 1.3574x over previous
//
#include <hip/hip_runtime.h>
#include <hip/hip_fp16.h>

typedef _Float16 half8 __attribute__((ext_vector_type(8)));
typedef float f32x4 __attribute__((ext_vector_type(4)));
typedef unsigned long long u64;

#define B_ 256
#define SEQ_ 512
#define D_ 256
#define H_ 1024
#define C_ 10
#define S_ 511
#define KB_ 40      // K=1280 / 32
#define NPK_ 2048   // packed output cols per direction (g|i interleaved per 64)
#define NTF_ 128    // NPK/16 fine n-tiles

#define SIGN64 0x8000800080008000ull
#define ABS64  0x7FFF7FFF7FFF7FFFull

// ---- workspace byte offsets ----
#define WPK_HALVES (2*KB_*NTF_*512)                    // 5,242,880 halves
#define EMBH_OFF   (WPK_HALVES*2)                      // 10,485,760
#define EMBH_HALVES (SEQ_*D_)                          // 131,072
#define HPK_OFF    (EMBH_OFF + EMBH_HALVES*2)          // 10,747,904
#define HPK_PER_PAR (2*32*16*64*8)                     // 524,288 halves per parity (both dirs)
#define HFIN_OFF   (HPK_OFF + 3*HPK_PER_PAR*2)         // triple-buffered h
#define HFIN_FLOATS (2*B_*H_)
#define BIAS_OFF   (HFIN_OFF + HFIN_FLOATS*4)
#define BAR_OFF    (BIAS_OFF + 2*NPK_*4)               // 8 groups x 32 flags x 16-word pad
#define BAR_WORDS  (8*32*16)
#define XT_OFF     (BAR_OFF + BAR_WORDS*4)             // transposed x: [SEQ][B] ints
#define XT_INTS    (SEQ_*B_)

__device__ __forceinline__ float fast_sigm(float x) {
    return __builtin_amdgcn_rcpf(1.f + __builtin_amdgcn_exp2f(-1.442695041f * x));
}
__device__ __forceinline__ float fast_tanh(float x) {
    return 1.f - 2.f * __builtin_amdgcn_rcpf(1.f + __builtin_amdgcn_exp2f(2.885390082f * x));
}

// h-part with data-embedded validity: poll fragments' sign bits (epoch-encoded),
// decode h = |e| - 1.5, MFMA. Depth-PFD rotating prefetch (atomic loads are not
// compiler-hoistable, so the pipeline is explicit).
template<int KO, int NH, int WB, int PFD>
__device__ __forceinline__ void h_poll(
    const _Float16* __restrict__ hrd, const half8 (&wfr)[10][4],
    f32x4 (&acc)[4][4], int mtblk, int lane, u64 expx)
{
    u64 ba[PFD][4], bb[PFD][4];
    auto issue = [&](int i, int s) {
        int kb2 = KO + i;
        #pragma unroll
        for (int mt = 0; mt < 4; ++mt) {
            const u64* p = (const u64*)(hrd + (size_t)((kb2*16 + (mtblk*4 + mt))*64 + lane)*8);
            ba[s][mt] = __hip_atomic_load(p,     __ATOMIC_RELAXED, __HIP_MEMORY_SCOPE_SYSTEM);
            bb[s][mt] = __hip_atomic_load(p + 1, __ATOMIC_RELAXED, __HIP_MEMORY_SCOPE_SYSTEM);
        }
    };
    #pragma unroll
    for (int i = 0; i < (NH < PFD ? NH : PFD); ++i) issue(i, i);
    #pragma unroll
    for (int i = 0; i < NH; ++i) {
        const int s = i % PFD;
        for (;;) {
            u64 o = (ba[s][0] ^ expx) | (bb[s][0] ^ expx) | (ba[s][1] ^ expx) | (bb[s][1] ^ expx)
                  | (ba[s][2] ^ expx) | (bb[s][2] ^ expx) | (ba[s][3] ^ expx) | (bb[s][3] ^ expx);
            bool ok = ((o & SIGN64) == 0);
            if (__all(ok)) break;
            __builtin_amdgcn_s_sleep(1);
            issue(i, s);
        }
        half8 a[4];
        #pragma unroll
        for (int mt = 0; mt < 4; ++mt) {
            u64 two[2] = { ba[s][mt] & ABS64, bb[s][mt] & ABS64 };
            half8 v; __builtin_memcpy(&v, two, 16);
            a[mt] = v - (_Float16)1.5f;
        }
        if (i + PFD < NH) issue(i + PFD, s);
        #pragma unroll
        for (int mt = 0; mt < 4; ++mt) {
            #pragma unroll
            for (int nt = 0; nt < 4; ++nt)
                acc[mt][nt] = __builtin_amdgcn_mfma_f32_16x16x32_f16(a[mt], wfr[WB + i][nt], acc[mt][nt], 0, 0, 0);
        }
    }
}

// Pack fp32 weights -> fp16 MFMA B-fragment-direct layout, emb -> fp16, biases packed,
// x -> transposed xT[t][m], zero barrier flags (ws is re-poisoned before every call).
__global__ void convert_kernel(
    const int* __restrict__ x, const float* __restrict__ emb,
    const float* __restrict__ Wgx_f, const float* __restrict__ Wgh_f, const float* __restrict__ bg_f,
    const float* __restrict__ Wix_f, const float* __restrict__ Wih_f, const float* __restrict__ bi_f,
    const float* __restrict__ Wgx_b, const float* __restrict__ Wgh_b, const float* __restrict__ bg_b,
    const float* __restrict__ Wix_b, const float* __restrict__ Wih_b, const float* __restrict__ bi_b,
    _Float16* __restrict__ Wpk, _Float16* __restrict__ embh, float* __restrict__ biaspk,
    unsigned* __restrict__ bar, int* __restrict__ xT)
{
    int idx = blockIdx.x * 256 + threadIdx.x;
    if (idx < WPK_HALVES) {
        int j = idx & 7;
        int L = (idx >> 3) & 63;
        int rest = idx >> 9;
        int ntf = rest & (NTF_ - 1);
        int rest2 = rest >> 7;
        int kb = rest2 % KB_;
        int d  = rest2 / KB_;
        int k = kb*32 + ((L >> 4) << 3) + j;
        int p = (ntf << 4) + (L & 15);
        int gate = (p >> 5) & 1;
        int u = ((p >> 6) << 5) + (p & 31);
        float v;
        if (k < D_) {
            const float* W = d ? (gate ? Wix_b : Wgx_b) : (gate ? Wix_f : Wgx_f);
            v = W[k*H_ + u];
        } else {
            const float* W = d ? (gate ? Wih_b : Wgh_b) : (gate ? Wih_f : Wgh_f);
            v = W[(k - D_)*H_ + u];
        }
        Wpk[idx] = (_Float16)v;
    } else if (idx < WPK_HALVES + EMBH_HALVES) {
        int i2 = idx - WPK_HALVES;
        embh[i2] = (_Float16)emb[i2];
    } else if (idx < WPK_HALVES + EMBH_HALVES + 2*NPK_) {
        int i3 = idx - (WPK_HALVES + EMBH_HALVES);
        int d = i3 >> 11;
        int p = i3 & (NPK_ - 1);
        int gate = (p >> 5) & 1;
        int u = ((p >> 6) << 5) + (p & 31);
        const float* bsrc = d ? (gate ? bi_b : bg_b) : (gate ? bi_f : bg_f);
        biaspk[i3] = bsrc[u];
    } else if (idx < WPK_HALVES + EMBH_HALVES + 2*NPK_ + BAR_WORDS) {
        bar[idx - (WPK_HALVES + EMBH_HALVES + 2*NPK_)] = 0u;
    } else if (idx < WPK_HALVES + EMBH_HALVES + 2*NPK_ + BAR_WORDS + XT_INTS) {
        int i5 = idx - (WPK_HALVES + EMBH_HALVES + 2*NPK_ + BAR_WORDS);
        int t = i5 >> 8;
        int m = i5 & (B_ - 1);
        xT[i5] = x[m*SEQ_ + t];
    }
}

// Persistent kernel: 256 blocks x 256 threads, 135KB LDS -> 1 block/CU (co-residency).
// blockIdx = ntb*8 + group, group = dir*4 + mtblk. W + c-state in registers.
// h triple-buffered (t%3), UC-exchanged, validity embedded as sign-epoch: e = +/-(1.5+h),
// epoch = ((t+1)/3)&1 at publish. Consumers poll data directly (no RAW flags).
// Flags only certify "step-t reads consumed" (WAR, 2 steps of slack, prefetched).
// LDS double-buffered by t&1 -> single mid-step barrier, no end-of-step drain.
__global__ __launch_bounds__(256, 1) void persistent_kernel(
    const int* __restrict__ xT, const _Float16* __restrict__ embh,
    const _Float16* __restrict__ Wpk, const float* __restrict__ biaspk,
    _Float16* __restrict__ hpk, float* __restrict__ hfinal,
    unsigned* __restrict__ bar)
{
    __shared__ float lds[2][4][64][66];

    int group = blockIdx.x & 7;
    int dir   = group >> 2;
    int mtblk = group & 3;
    int ntb   = blockIdx.x >> 3;
    int w    = threadIdx.x >> 6;
    int lane = threadIdx.x & 63;
    int q    = lane >> 4;
    int c16  = lane & 15;
    int u0   = q * 8;               // epilogue: 8 consecutive units per thread
    int kb0  = w * 10;              // wave w owns kbs [10w, 10w+10)

    unsigned* gflags = bar + group * (32*16);
    const _Float16* Wd = Wpk + (size_t)dir * (KB_*NTF_*512);

    // ---- preload W fragments into registers (160 VGPRs/lane) ----
    half8 wfr[10][4];
    #pragma unroll
    for (int kk = 0; kk < 10; ++kk) {
        #pragma unroll
        for (int nt = 0; nt < 4; ++nt)
            wfr[kk][nt] = *(const half8*)(Wd + (((size_t)(kb0 + kk)*NTF_ + (ntb*4 + nt))*64 + lane)*8);
    }

    // ---- preload epilogue biases ----
    float bgr[8], bir[8];
    #pragma unroll
    for (int j = 0; j < 8; ++j) {
        bgr[j] = biaspk[dir*NPK_ + ntb*64 + u0 + j];
        bir[j] = biaspk[dir*NPK_ + ntb*64 + 32 + u0 + j];
    }

    // ---- c-state in registers ----
    float creg[8];
    #pragma unroll
    for (int j = 0; j < 8; ++j) creg[j] = 0.f;

    #pragma unroll 1
    for (int t = 0; t < S_; ++t) {
        const _Float16* hrd = hpk + (size_t)(t % 3) * HPK_PER_PAR + dir*(32*16*64*8);
        _Float16*       hwr = hpk + (size_t)((t + 1) % 3) * HPK_PER_PAR + dir*(32*16*64*8);
        int rep = (t / 3) & 1;            // expected epoch of data read at step t
        int wep = ((t + 1) / 3) & 1;      // epoch encoded into data published at step t
        u64 expx = rep ? SIGN64 : 0ull;
        int par = t & 1;                  // LDS buffer parity
        int t_eff = dir ? (S_ - 1 - t) : t;

        int xr[4] = {0, 0, 0, 0};
        if (w == 0) {
            #pragma unroll
            for (int mt = 0; mt < 4; ++mt)
                xr[mt] = xT[t_eff*B_ + mtblk*64 + mt*16 + c16];
        }

        f32x4 acc[4][4];
        #pragma unroll
        for (int a = 0; a < 4; ++a)
            #pragma unroll
            for (int b = 0; b < 4; ++b) {
                acc[a][b][0] = 0.f; acc[a][b][1] = 0.f; acc[a][b][2] = 0.f; acc[a][b][3] = 0.f;
            }

        // ---- x-part (wave 0 only; plain cached loads) ----
        #pragma unroll
        for (int kk = 0; kk < 10; ++kk) {
            int kb = kb0 + kk;
            if (kb < 8) {
                half8 a[4];
                #pragma unroll
                for (int mt = 0; mt < 4; ++mt)
                    a[mt] = *(const half8*)(embh + xr[mt]*D_ + kb*32 + q*8);
                #pragma unroll
                for (int mt = 0; mt < 4; ++mt) {
                    #pragma unroll
                    for (int nt = 0; nt < 4; ++nt)
                        acc[mt][nt] = __builtin_amdgcn_mfma_f32_16x16x32_f16(a[mt], wfr[kk][nt], acc[mt][nt], 0, 0, 0);
                }
            }
        }

        // ---- h-part: data-validity poll + decode + MFMA (no flag wait) ----
        if (t > 0) {
            if (w == 0)      h_poll<0, 2, 8, 2>(hrd, wfr, acc, mtblk, lane, expx);
            else if (w == 1) h_poll<2, 10, 0, 4>(hrd, wfr, acc, mtblk, lane, expx);
            else if (w == 2) h_poll<12, 10, 0, 4>(hrd, wfr, acc, mtblk, lane, expx);
            else             h_poll<22, 10, 0, 4>(hrd, wfr, acc, mtblk, lane, expx);
        }

        // ---- K-split partials -> LDS (double-buffered by t&1) ----
        #pragma unroll
        for (int mt = 0; mt < 4; ++mt) {
            #pragma unroll
            for (int nt = 0; nt < 4; ++nt) {
                #pragma unroll
                for (int r = 0; r < 4; ++r)
                    lds[par][w][mt*16 + q*4 + r][nt*16 + c16] = acc[mt][nt][r];
            }
        }
        __syncthreads();   // the ONLY barrier per step

        // ---- WAR flag: this block's step-t reads are consumed (MFMAs executed) ----
        if (t < S_ - 1 && threadIdx.x == 0)
            __hip_atomic_store(&gflags[ntb*16], (unsigned)t, __ATOMIC_RELAXED, __HIP_MEMORY_SCOPE_SYSTEM);

        // ---- prefetch WAR certificate (checked just before publish) ----
        bool need_war = (t >= 2 && t < S_ - 1);
        unsigned fv = 0u;
        if (need_war && lane < 32)
            fv = __hip_atomic_load(&gflags[lane*16], __ATOMIC_RELAXED, __HIP_MEMORY_SCOPE_SYSTEM);

        // ---- epilogue: reduce + gates + encode + publish ----
        {
            int mloc = w*16 + c16;
            int mg   = mtblk*64 + mloc;
            half8 hv;
            float hf[8];
            #pragma unroll
            for (int j = 0; j < 8; ++j) {
                float zg = lds[par][0][mloc][u0 + j] + lds[par][1][mloc][u0 + j]
                         + lds[par][2][mloc][u0 + j] + lds[par][3][mloc][u0 + j] + bgr[j];
                float zi = lds[par][0][mloc][32 + u0 + j] + lds[par][1][mloc][32 + u0 + j]
                         + lds[par][2][mloc][32 + u0 + j] + lds[par][3][mloc][32 + u0 + j] + bir[j];
                float g  = fast_tanh(zg);
                float ii = fast_sigm(zi);
                float cn = ii * (g + creg[j]);
                creg[j] = cn;
                float h = fast_tanh(cn) * ii;
                float e = h + 1.5f;
                hv[j] = (_Float16)(wep ? -e : e);
                hf[j] = h;
            }
            if (t == S_ - 1) {
                #pragma unroll
                for (int j = 0; j < 8; ++j)
                    hfinal[dir*(B_*H_) + mg*H_ + ntb*32 + u0 + j] = hf[j];
            } else {
                if (need_war) {
                    for (;;) {
                        bool ok = (lane >= 32) || (fv >= (unsigned)(t - 2));
                        if (__all(ok)) break;
                        __builtin_amdgcn_s_sleep(2);
                        if (lane < 32)
                            fv = __hip_atomic_load(&gflags[lane*16], __ATOMIC_RELAXED, __HIP_MEMORY_SCOPE_SYSTEM);
                    }
                }
                // publish encoded h (UC system-scope); no drain, no flag on RAW path
                u64 two[2];
                __builtin_memcpy(two, &hv, 16);
                u64* base = (u64*)(hwr + ((size_t)((ntb*16 + mtblk*4 + w)*64 + lane) * 8));
                __hip_atomic_store(base,     two[0], __ATOMIC_RELAXED, __HIP_MEMORY_SCOPE_SYSTEM);
                __hip_atomic_store(base + 1, two[1], __ATOMIC_RELAXED, __HIP_MEMORY_SCOPE_SYSTEM);
            }
        }
    }
}

// out[b][c] = [hf|hb] @ Wp + bp
__global__ void proj_kernel(const float* __restrict__ hfinal,
                            const float* __restrict__ Wp, const float* __restrict__ bp,
                            float* __restrict__ out)
{
    int b = blockIdx.x;
    int lane = threadIdx.x;
    float s[C_];
    #pragma unroll
    for (int c = 0; c < C_; ++c) s[c] = 0.f;
    for (int j = lane; j < 2*H_; j += 64) {
        float hv = (j < H_) ? hfinal[b*H_ + j] : hfinal[B_*H_ + b*H_ + (j - H_)];
        const float* wr = Wp + j*C_;
        #pragma unroll
        for (int c = 0; c < C_; ++c) s[c] += hv * wr[c];
    }
    #pragma unroll
    for (int off = 32; off > 0; off >>= 1) {
        #pragma unroll
        for (int c = 0; c < C_; ++c) s[c] += __shfl_down(s[c], off);
    }
    if (lane == 0) {
        #pragma unroll
        for (int c = 0; c < C_; ++c) out[b*C_ + c] = s[c] + bp[c];
    }
}

extern "C" void kernel_launch(void* const* d_in, const int* in_sizes, int n_in,
                              void* d_out, int out_size, void* d_ws, size_t ws_size,
                              hipStream_t stream)
{
    const int*   x     = (const int*)d_in[0];
    const float* emb   = (const float*)d_in[1];
    const float* Wgx_f = (const float*)d_in[2];
    const float* Wgh_f = (const float*)d_in[3];
    const float* bg_f  = (const float*)d_in[4];
    const float* Wix_f = (const float*)d_in[5];
    const float* Wih_f = (const float*)d_in[6];
    const float* bi_f  = (const float*)d_in[7];
    const float* Wgx_b = (const float*)d_in[8];
    const float* Wgh_b = (const float*)d_in[9];
    const float* bg_b  = (const float*)d_in[10];
    const float* Wix_b = (const float*)d_in[11];
    const float* Wih_b = (const float*)d_in[12];
    const float* bi_b  = (const float*)d_in[13];
    const float* Wp    = (const float*)d_in[14];
    const float* bp    = (const float*)d_in[15];
    float* out = (float*)d_out;

    char* ws = (char*)d_ws;
    _Float16* Wpk    = (_Float16*)(ws + 0);
    _Float16* embh   = (_Float16*)(ws + EMBH_OFF);
    _Float16* hpk    = (_Float16*)(ws + HPK_OFF);
    float*    hfinal = (float*)(ws + HFIN_OFF);
    float*    biaspk = (float*)(ws + BIAS_OFF);
    unsigned* bar    = (unsigned*)(ws + BAR_OFF);
    int*      xT     = (int*)(ws + XT_OFF);

    int total = WPK_HALVES + EMBH_HALVES + 2*NPK_ + BAR_WORDS + XT_INTS;
    convert_kernel<<<(total + 255)/256, 256, 0, stream>>>(
        x, emb, Wgx_f, Wgh_f, bg_f, Wix_f, Wih_f, bi_f,
        Wgx_b, Wgh_b, bg_b, Wix_b, Wih_b, bi_b, Wpk, embh, biaspk, bar, xT);

    persistent_kernel<<<256, 256, 0, stream>>>(xT, embh, Wpk, biaspk, hpk, hfinal, bar);

    proj_kernel<<<B_, 64, 0, stream>>>(hfinal, Wp, bp, out);
}